// Round 1
// baseline (550.974 us; speedup 1.0000x reference)
//
#include <hip/hip_runtime.h>
#include <cstdint>
#include <cstddef>

#define T_TOK 8192
#define H_DIM 512
#define E_NUM 16
#define F_DIM 1024

typedef __bf16 bf16x8 __attribute__((ext_vector_type(8)));
typedef float f32x4 __attribute__((ext_vector_type(4)));

// LDS row stride in bf16 elements: 112B rows -> 16B aligned, 2-way bank aliasing (free)
#define LDST 56

// ws layout (bytes)
#define OFF_XBF  0UL
#define OFF_HID  8388608UL          // 8192*512*2
#define OFF_STOK 42074112UL         // OFF_HID + (16384+64)*1024*2
#define OFF_SW   42139648UL
#define OFF_TOPE 42205184UL
#define OFF_TOPW 42270720UL
#define OFF_CNT  42336256UL
#define OFF_CUR  42336320UL
#define OFF_OFFS 42336384UL

__device__ __forceinline__ unsigned short f2bf(float f) {
  union { float f; uint32_t u; } v; v.f = f;
  uint32_t r = v.u + 0x7fffu + ((v.u >> 16) & 1u);
  return (unsigned short)(r >> 16);
}

// ---------------- routing: wave per token ----------------
__global__ __launch_bounds__(256) void k_router(
    const float* __restrict__ x, const float* __restrict__ rw,
    unsigned short* __restrict__ xbf, int* __restrict__ tope,
    float* __restrict__ topw, int* __restrict__ counts) {
  const int wave = threadIdx.x >> 6, lane = threadIdx.x & 63;
  const int t = blockIdx.x * 4 + wave;
  const float4* xr = (const float4*)(x + (size_t)t * H_DIM + lane * 8);
  float4 a = xr[0], b = xr[1];
  float xi[8] = {a.x, a.y, a.z, a.w, b.x, b.y, b.z, b.w};
  // bf16 copy of x for the MFMA path
  uint4 o;
  o.x = (uint32_t)f2bf(xi[0]) | ((uint32_t)f2bf(xi[1]) << 16);
  o.y = (uint32_t)f2bf(xi[2]) | ((uint32_t)f2bf(xi[3]) << 16);
  o.z = (uint32_t)f2bf(xi[4]) | ((uint32_t)f2bf(xi[5]) << 16);
  o.w = (uint32_t)f2bf(xi[6]) | ((uint32_t)f2bf(xi[7]) << 16);
  *(uint4*)(xbf + (size_t)t * H_DIM + lane * 8) = o;
  // fp32 router logits (selection must match the fp32 reference)
  float acc[E_NUM];
  #pragma unroll
  for (int e = 0; e < E_NUM; ++e) {
    const float4* wr = (const float4*)(rw + e * H_DIM + lane * 8);
    float4 wa = wr[0], wb = wr[1];
    acc[e] = xi[0]*wa.x + xi[1]*wa.y + xi[2]*wa.z + xi[3]*wa.w
           + xi[4]*wb.x + xi[5]*wb.y + xi[6]*wb.z + xi[7]*wb.w;
  }
  #pragma unroll
  for (int off = 1; off < 64; off <<= 1) {
    #pragma unroll
    for (int e = 0; e < E_NUM; ++e) acc[e] += __shfl_xor(acc[e], off);
  }
  if (lane == 0) {
    int e0 = 0; float v0 = acc[0];
    #pragma unroll
    for (int e = 1; e < E_NUM; ++e) if (acc[e] > v0) { v0 = acc[e]; e0 = e; }
    int e1 = -1; float v1 = -3.4e38f;
    #pragma unroll
    for (int e = 0; e < E_NUM; ++e) if (e != e0 && acc[e] > v1) { v1 = acc[e]; e1 = e; }
    float ee = __expf(v1 - v0);
    float inv = 1.0f / (1.0f + ee);
    tope[t*2]   = e0; tope[t*2+1] = e1;
    topw[t*2]   = inv; topw[t*2+1] = ee * inv;
    atomicAdd(&counts[e0], 1);
    atomicAdd(&counts[e1], 1);
  }
}

__global__ void k_offsets(const int* __restrict__ counts, int* __restrict__ offs) {
  if (threadIdx.x == 0 && blockIdx.x == 0) {
    int s = 0;
    for (int e = 0; e < E_NUM; ++e) { offs[e] = s; s += counts[e]; }
    offs[E_NUM] = s;
  }
}

__global__ __launch_bounds__(256) void k_scatter(
    const int* __restrict__ tope, const float* __restrict__ topw,
    const int* __restrict__ offs, int* __restrict__ cursors,
    int* __restrict__ stok, float* __restrict__ sw) {
  int t = blockIdx.x * 256 + threadIdx.x;
  #pragma unroll
  for (int k = 0; k < 2; ++k) {
    int e = tope[t*2+k];
    int pos = atomicAdd(&cursors[e], 1);
    int slot = offs[e] + pos;
    stok[slot] = t;
    sw[slot] = topw[t*2+k];
  }
}

// ---------------- gate/up GEMM + SiLU: hid = silu(x@Wg) * (x@Wu) ----------------
// block: 256 thr (4 waves). tile: 64 tokens x 64 F-cols, K-chunk 32 over H=512.
__global__ __launch_bounds__(256) void k_gateup(
    const unsigned short* __restrict__ xbf,
    const float* __restrict__ gw, const float* __restrict__ uw,
    const int* __restrict__ stok, const int* __restrict__ counts,
    const int* __restrict__ offs, unsigned short* __restrict__ hid) {
  const int e = blockIdx.z;
  const int cnt = counts[e];
  const int t0 = blockIdx.y * 64;
  if (t0 >= cnt) return;
  const int base = offs[e];
  const int f0 = blockIdx.x * 64;
  const float* gwe = gw + (size_t)e * H_DIM * F_DIM;
  const float* uwe = uw + (size_t)e * H_DIM * F_DIM;

  __shared__ __align__(16) unsigned short lA[64 * LDST];
  __shared__ __align__(16) unsigned short lG[64 * LDST];
  __shared__ __align__(16) unsigned short lU[64 * LDST];

  const int tid = threadIdx.x;
  const int wave = tid >> 6, lane = tid & 63;
  // A staging: 4 threads per row, 16B each
  const int ar = tid >> 2, ap = tid & 3;
  const int aslot = t0 + ar;
  const int atok = stok[base + min(aslot, cnt - 1)];
  const uint4* asrc = (const uint4*)(xbf + (size_t)atok * H_DIM);

  f32x4 accg[4] = {}; f32x4 accu[4] = {};

  for (int kk = 0; kk < 16; ++kk) {
    __syncthreads();
    // stage A chunk [64 rows][32 k]
    *(uint4*)&lA[ar * LDST + ap * 8] = asrc[kk * 4 + ap];
    // stage Wg/Wu chunks transposed: lW[f][k], convert fp32->bf16 inline
    #pragma unroll
    for (int i = 0; i < 2; ++i) {
      int task = tid + i * 256;           // 512 tasks: 32 k x 16 f4-groups
      int k  = task >> 4;
      int f4 = (task & 15) * 4;
      float4 g = *(const float4*)&gwe[(kk*32 + k) * F_DIM + f0 + f4];
      lG[(f4+0)*LDST + k] = f2bf(g.x);
      lG[(f4+1)*LDST + k] = f2bf(g.y);
      lG[(f4+2)*LDST + k] = f2bf(g.z);
      lG[(f4+3)*LDST + k] = f2bf(g.w);
      float4 u = *(const float4*)&uwe[(kk*32 + k) * F_DIM + f0 + f4];
      lU[(f4+0)*LDST + k] = f2bf(u.x);
      lU[(f4+1)*LDST + k] = f2bf(u.y);
      lU[(f4+2)*LDST + k] = f2bf(u.z);
      lU[(f4+3)*LDST + k] = f2bf(u.w);
    }
    __syncthreads();
    bf16x8 afrag = *(const bf16x8*)&lA[(wave*16 + (lane & 15)) * LDST + (lane >> 4) * 8];
    #pragma unroll
    for (int s = 0; s < 4; ++s) {
      bf16x8 bg = *(const bf16x8*)&lG[(s*16 + (lane & 15)) * LDST + (lane >> 4) * 8];
      accg[s] = __builtin_amdgcn_mfma_f32_16x16x32_bf16(afrag, bg, accg[s], 0, 0, 0);
      bf16x8 bu = *(const bf16x8*)&lU[(s*16 + (lane & 15)) * LDST + (lane >> 4) * 8];
      accu[s] = __builtin_amdgcn_mfma_f32_16x16x32_bf16(afrag, bu, accu[s], 0, 0, 0);
    }
  }
  // epilogue: silu(g)*u -> bf16 hid
  const int row_l = (lane >> 4) * 4, col = lane & 15;
  #pragma unroll
  for (int s = 0; s < 4; ++s) {
    #pragma unroll
    for (int r = 0; r < 4; ++r) {
      int sl = t0 + wave*16 + row_l + r;
      if (sl < cnt) {
        float g = accg[s][r], u = accu[s][r];
        float h = g / (1.0f + __expf(-g)) * u;
        hid[(size_t)(base + sl) * F_DIM + f0 + s*16 + col] = f2bf(h);
      }
    }
  }
}

// ---------------- down GEMM + weighted scatter: out += w * (hid @ Wd) ----------------
__global__ __launch_bounds__(256) void k_down(
    const unsigned short* __restrict__ hid, const float* __restrict__ dw,
    const int* __restrict__ stok, const float* __restrict__ sw,
    const int* __restrict__ counts, const int* __restrict__ offs,
    float* __restrict__ out) {
  const int e = blockIdx.z;
  const int cnt = counts[e];
  const int t0 = blockIdx.y * 64;
  if (t0 >= cnt) return;
  const int base = offs[e];
  const int h0 = blockIdx.x * 64;
  const float* dwe = dw + (size_t)e * F_DIM * H_DIM;

  __shared__ __align__(16) unsigned short lA[64 * LDST];
  __shared__ __align__(16) unsigned short lW[64 * LDST];

  const int tid = threadIdx.x;
  const int wave = tid >> 6, lane = tid & 63;
  const int ar = tid >> 2, ap = tid & 3;
  const uint4* asrc = (const uint4*)(hid + (size_t)(base + t0 + ar) * F_DIM);

  f32x4 acc[4] = {};

  for (int kk = 0; kk < 32; ++kk) {
    __syncthreads();
    *(uint4*)&lA[ar * LDST + ap * 8] = asrc[kk * 4 + ap];
    #pragma unroll
    for (int i = 0; i < 2; ++i) {
      int task = tid + i * 256;
      int k  = task >> 4;
      int f4 = (task & 15) * 4;
      float4 d = *(const float4*)&dwe[(kk*32 + k) * H_DIM + h0 + f4];
      lW[(f4+0)*LDST + k] = f2bf(d.x);
      lW[(f4+1)*LDST + k] = f2bf(d.y);
      lW[(f4+2)*LDST + k] = f2bf(d.z);
      lW[(f4+3)*LDST + k] = f2bf(d.w);
    }
    __syncthreads();
    bf16x8 afrag = *(const bf16x8*)&lA[(wave*16 + (lane & 15)) * LDST + (lane >> 4) * 8];
    #pragma unroll
    for (int s = 0; s < 4; ++s) {
      bf16x8 bw = *(const bf16x8*)&lW[(s*16 + (lane & 15)) * LDST + (lane >> 4) * 8];
      acc[s] = __builtin_amdgcn_mfma_f32_16x16x32_bf16(afrag, bw, acc[s], 0, 0, 0);
    }
  }
  const int row_l = (lane >> 4) * 4, col = lane & 15;
  #pragma unroll
  for (int s = 0; s < 4; ++s) {
    #pragma unroll
    for (int r = 0; r < 4; ++r) {
      int sl = t0 + wave*16 + row_l + r;
      if (sl < cnt) {
        int slot = base + sl;
        // exactly 2 atomic contributions per out element from 0 -> order-invariant (a+b==b+a)
        atomicAdd(&out[(size_t)stok[slot] * H_DIM + h0 + s*16 + col], sw[slot] * acc[s][r]);
      }
    }
  }
}

extern "C" void kernel_launch(void* const* d_in, const int* in_sizes, int n_in,
                              void* d_out, int out_size, void* d_ws, size_t ws_size,
                              hipStream_t stream) {
  const float* x  = (const float*)d_in[0];
  const float* rw = (const float*)d_in[1];
  const float* gw = (const float*)d_in[2];
  const float* uw = (const float*)d_in[3];
  const float* dw = (const float*)d_in[4];
  float* out = (float*)d_out;
  char* ws = (char*)d_ws;

  unsigned short* xbf = (unsigned short*)(ws + OFF_XBF);
  unsigned short* hid = (unsigned short*)(ws + OFF_HID);
  int*   stok    = (int*)(ws + OFF_STOK);
  float* swt     = (float*)(ws + OFF_SW);
  int*   tope    = (int*)(ws + OFF_TOPE);
  float* topw    = (float*)(ws + OFF_TOPW);
  int*   counts  = (int*)(ws + OFF_CNT);
  int*   cursors = (int*)(ws + OFF_CUR);
  int*   offs    = (int*)(ws + OFF_OFFS);

  hipMemsetAsync(ws + OFF_CNT, 0, 256, stream);
  hipMemsetAsync(d_out, 0, (size_t)T_TOK * H_DIM * sizeof(float), stream);

  k_router<<<T_TOK / 4, 256, 0, stream>>>(x, rw, xbf, tope, topw, counts);
  k_offsets<<<1, 64, 0, stream>>>(counts, offs);
  k_scatter<<<T_TOK / 256, 256, 0, stream>>>(tope, topw, offs, cursors, stok, swt);
  k_gateup<<<dim3(F_DIM / 64, T_TOK / 64, E_NUM), 256, 0, stream>>>(
      xbf, gw, uw, stok, counts, offs, hid);
  k_down<<<dim3(H_DIM / 64, T_TOK / 64, E_NUM), 256, 0, stream>>>(
      hid, dw, stok, swt, counts, offs, out);
}

// Round 2
// 326.474 us; speedup vs baseline: 1.6877x; 1.6877x over previous
//
#include <hip/hip_runtime.h>
#include <cstdint>
#include <cstddef>

#define T_TOK 8192
#define H_DIM 512
#define E_NUM 16
#define F_DIM 1024

typedef __bf16 bf16x8 __attribute__((ext_vector_type(8)));
typedef float f32x4 __attribute__((ext_vector_type(4)));

// LDS row stride in bf16 elements: 112B rows -> 16B aligned, 2-way bank aliasing (free)
#define LDST 56

// ws layout (bytes)
#define OFF_XBF  0UL
#define OFF_HID  8388608UL           // 8192*512*2
#define OFF_STOK 42074112UL          // OFF_HID + (16384+64)*1024*2
#define OFF_SW   42140160UL
#define OFF_TOPE 42206208UL
#define OFF_TOPW 42271744UL
#define OFF_CNT  42337280UL          // 16 experts * 16 ints (cacheline-padded)
#define OFF_CUR  42338304UL          // 16 experts * 16 ints (cacheline-padded)
#define OFF_OFFS 42339328UL

__device__ __forceinline__ unsigned short f2bf(float f) {
  union { float f; uint32_t u; } v; v.f = f;
  uint32_t r = v.u + 0x7fffu + ((v.u >> 16) & 1u);
  return (unsigned short)(r >> 16);
}

// ---------------- routing: wave per token (NO global atomics) ----------------
__global__ __launch_bounds__(256) void k_router(
    const float* __restrict__ x, const float* __restrict__ rw,
    unsigned short* __restrict__ xbf, int* __restrict__ tope,
    float* __restrict__ topw) {
  const int wave = threadIdx.x >> 6, lane = threadIdx.x & 63;
  const int t = blockIdx.x * 4 + wave;
  const float4* xr = (const float4*)(x + (size_t)t * H_DIM + lane * 8);
  float4 a = xr[0], b = xr[1];
  float xi[8] = {a.x, a.y, a.z, a.w, b.x, b.y, b.z, b.w};
  // bf16 copy of x for the MFMA path
  uint4 o;
  o.x = (uint32_t)f2bf(xi[0]) | ((uint32_t)f2bf(xi[1]) << 16);
  o.y = (uint32_t)f2bf(xi[2]) | ((uint32_t)f2bf(xi[3]) << 16);
  o.z = (uint32_t)f2bf(xi[4]) | ((uint32_t)f2bf(xi[5]) << 16);
  o.w = (uint32_t)f2bf(xi[6]) | ((uint32_t)f2bf(xi[7]) << 16);
  *(uint4*)(xbf + (size_t)t * H_DIM + lane * 8) = o;
  // fp32 router logits (selection must match the fp32 reference)
  float acc[E_NUM];
  #pragma unroll
  for (int e = 0; e < E_NUM; ++e) {
    const float4* wr = (const float4*)(rw + e * H_DIM + lane * 8);
    float4 wa = wr[0], wb = wr[1];
    acc[e] = xi[0]*wa.x + xi[1]*wa.y + xi[2]*wa.z + xi[3]*wa.w
           + xi[4]*wb.x + xi[5]*wb.y + xi[6]*wb.z + xi[7]*wb.w;
  }
  #pragma unroll
  for (int off = 1; off < 64; off <<= 1) {
    #pragma unroll
    for (int e = 0; e < E_NUM; ++e) acc[e] += __shfl_xor(acc[e], off);
  }
  if (lane == 0) {
    int e0 = 0; float v0 = acc[0];
    #pragma unroll
    for (int e = 1; e < E_NUM; ++e) if (acc[e] > v0) { v0 = acc[e]; e0 = e; }
    int e1 = -1; float v1 = -3.4e38f;
    #pragma unroll
    for (int e = 0; e < E_NUM; ++e) if (e != e0 && acc[e] > v1) { v1 = acc[e]; e1 = e; }
    float ee = __expf(v1 - v0);
    float inv = 1.0f / (1.0f + ee);
    tope[t*2]   = e0; tope[t*2+1] = e1;
    topw[t*2]   = inv; topw[t*2+1] = ee * inv;
  }
}

// ---------------- histogram: LDS-aggregated, padded global counters ----------------
__global__ __launch_bounds__(256) void k_hist(
    const int* __restrict__ tope, int* __restrict__ counts) {
  __shared__ int lh[E_NUM];
  const int tid = threadIdx.x;
  if (tid < E_NUM) lh[tid] = 0;
  __syncthreads();
  int e = tope[blockIdx.x * 256 + tid];
  atomicAdd(&lh[e], 1);
  __syncthreads();
  if (tid < E_NUM) atomicAdd(&counts[tid * 16], lh[tid]);
}

__global__ void k_offsets(const int* __restrict__ counts, int* __restrict__ offs) {
  if (threadIdx.x == 0 && blockIdx.x == 0) {
    int s = 0;
    for (int e = 0; e < E_NUM; ++e) { offs[e] = s; s += counts[e * 16]; }
    offs[E_NUM] = s;
  }
}

// ---------------- scatter: block-aggregated ranks, padded global cursors ----------------
__global__ __launch_bounds__(256) void k_scatter(
    const int* __restrict__ tope, const float* __restrict__ topw,
    const int* __restrict__ offs, int* __restrict__ cursors,
    int* __restrict__ stok, float* __restrict__ sw) {
  __shared__ int lh[E_NUM];
  __shared__ int lbase[E_NUM];
  const int tid = threadIdx.x;
  const int t = blockIdx.x * 256 + tid;
  if (tid < E_NUM) lh[tid] = 0;
  __syncthreads();
  int e0 = tope[t*2], e1 = tope[t*2+1];
  int r0 = atomicAdd(&lh[e0], 1);
  int r1 = atomicAdd(&lh[e1], 1);
  __syncthreads();
  if (tid < E_NUM) lbase[tid] = atomicAdd(&cursors[tid * 16], lh[tid]);
  __syncthreads();
  int s0 = offs[e0] + lbase[e0] + r0;
  int s1 = offs[e1] + lbase[e1] + r1;
  stok[s0] = t; sw[s0] = topw[t*2];
  stok[s1] = t; sw[s1] = topw[t*2+1];
}

// ---------------- gate/up GEMM + SiLU: hid = silu(x@Wg) * (x@Wu) ----------------
// block: 256 thr (4 waves). tile: 64 tokens x 64 F-cols, K-chunk 32 over H=512.
__global__ __launch_bounds__(256) void k_gateup(
    const unsigned short* __restrict__ xbf,
    const float* __restrict__ gw, const float* __restrict__ uw,
    const int* __restrict__ stok, const int* __restrict__ counts,
    const int* __restrict__ offs, unsigned short* __restrict__ hid) {
  const int e = blockIdx.z;
  const int cnt = counts[e * 16];
  const int t0 = blockIdx.y * 64;
  if (t0 >= cnt) return;
  const int base = offs[e];
  const int f0 = blockIdx.x * 64;
  const float* gwe = gw + (size_t)e * H_DIM * F_DIM;
  const float* uwe = uw + (size_t)e * H_DIM * F_DIM;

  __shared__ __align__(16) unsigned short lA[64 * LDST];
  __shared__ __align__(16) unsigned short lG[64 * LDST];
  __shared__ __align__(16) unsigned short lU[64 * LDST];

  const int tid = threadIdx.x;
  const int wave = tid >> 6, lane = tid & 63;
  // A staging: 4 threads per row, 16B each
  const int ar = tid >> 2, ap = tid & 3;
  const int aslot = t0 + ar;
  const int atok = stok[base + min(aslot, cnt - 1)];
  const uint4* asrc = (const uint4*)(xbf + (size_t)atok * H_DIM);

  f32x4 accg[4] = {}; f32x4 accu[4] = {};

  for (int kk = 0; kk < 16; ++kk) {
    __syncthreads();
    // stage A chunk [64 rows][32 k]
    *(uint4*)&lA[ar * LDST + ap * 8] = asrc[kk * 4 + ap];
    // stage Wg/Wu chunks transposed: lW[f][k], convert fp32->bf16 inline
    #pragma unroll
    for (int i = 0; i < 2; ++i) {
      int task = tid + i * 256;           // 512 tasks: 32 k x 16 f4-groups
      int k  = task >> 4;
      int f4 = (task & 15) * 4;
      float4 g = *(const float4*)&gwe[(kk*32 + k) * F_DIM + f0 + f4];
      lG[(f4+0)*LDST + k] = f2bf(g.x);
      lG[(f4+1)*LDST + k] = f2bf(g.y);
      lG[(f4+2)*LDST + k] = f2bf(g.z);
      lG[(f4+3)*LDST + k] = f2bf(g.w);
      float4 u = *(const float4*)&uwe[(kk*32 + k) * F_DIM + f0 + f4];
      lU[(f4+0)*LDST + k] = f2bf(u.x);
      lU[(f4+1)*LDST + k] = f2bf(u.y);
      lU[(f4+2)*LDST + k] = f2bf(u.z);
      lU[(f4+3)*LDST + k] = f2bf(u.w);
    }
    __syncthreads();
    bf16x8 afrag = *(const bf16x8*)&lA[(wave*16 + (lane & 15)) * LDST + (lane >> 4) * 8];
    #pragma unroll
    for (int s = 0; s < 4; ++s) {
      bf16x8 bg = *(const bf16x8*)&lG[(s*16 + (lane & 15)) * LDST + (lane >> 4) * 8];
      accg[s] = __builtin_amdgcn_mfma_f32_16x16x32_bf16(afrag, bg, accg[s], 0, 0, 0);
      bf16x8 bu = *(const bf16x8*)&lU[(s*16 + (lane & 15)) * LDST + (lane >> 4) * 8];
      accu[s] = __builtin_amdgcn_mfma_f32_16x16x32_bf16(afrag, bu, accu[s], 0, 0, 0);
    }
  }
  // epilogue: silu(g)*u -> bf16 hid
  const int row_l = (lane >> 4) * 4, col = lane & 15;
  #pragma unroll
  for (int s = 0; s < 4; ++s) {
    #pragma unroll
    for (int r = 0; r < 4; ++r) {
      int sl = t0 + wave*16 + row_l + r;
      if (sl < cnt) {
        float g = accg[s][r], u = accu[s][r];
        float h = g / (1.0f + __expf(-g)) * u;
        hid[(size_t)(base + sl) * F_DIM + f0 + s*16 + col] = f2bf(h);
      }
    }
  }
}

// ---------------- down GEMM + weighted scatter: out += w * (hid @ Wd) ----------------
__global__ __launch_bounds__(256) void k_down(
    const unsigned short* __restrict__ hid, const float* __restrict__ dw,
    const int* __restrict__ stok, const float* __restrict__ sw,
    const int* __restrict__ counts, const int* __restrict__ offs,
    float* __restrict__ out) {
  const int e = blockIdx.z;
  const int cnt = counts[e * 16];
  const int t0 = blockIdx.y * 64;
  if (t0 >= cnt) return;
  const int base = offs[e];
  const int h0 = blockIdx.x * 64;
  const float* dwe = dw + (size_t)e * F_DIM * H_DIM;

  __shared__ __align__(16) unsigned short lA[64 * LDST];
  __shared__ __align__(16) unsigned short lW[64 * LDST];

  const int tid = threadIdx.x;
  const int wave = tid >> 6, lane = tid & 63;
  const int ar = tid >> 2, ap = tid & 3;
  const uint4* asrc = (const uint4*)(hid + (size_t)(base + t0 + ar) * F_DIM);

  f32x4 acc[4] = {};

  for (int kk = 0; kk < 32; ++kk) {
    __syncthreads();
    *(uint4*)&lA[ar * LDST + ap * 8] = asrc[kk * 4 + ap];
    #pragma unroll
    for (int i = 0; i < 2; ++i) {
      int task = tid + i * 256;
      int k  = task >> 4;
      int f4 = (task & 15) * 4;
      float4 d = *(const float4*)&dwe[(kk*32 + k) * H_DIM + h0 + f4];
      lW[(f4+0)*LDST + k] = f2bf(d.x);
      lW[(f4+1)*LDST + k] = f2bf(d.y);
      lW[(f4+2)*LDST + k] = f2bf(d.z);
      lW[(f4+3)*LDST + k] = f2bf(d.w);
    }
    __syncthreads();
    bf16x8 afrag = *(const bf16x8*)&lA[(wave*16 + (lane & 15)) * LDST + (lane >> 4) * 8];
    #pragma unroll
    for (int s = 0; s < 4; ++s) {
      bf16x8 bw = *(const bf16x8*)&lW[(s*16 + (lane & 15)) * LDST + (lane >> 4) * 8];
      acc[s] = __builtin_amdgcn_mfma_f32_16x16x32_bf16(afrag, bw, acc[s], 0, 0, 0);
    }
  }
  const int row_l = (lane >> 4) * 4, col = lane & 15;
  #pragma unroll
  for (int s = 0; s < 4; ++s) {
    #pragma unroll
    for (int r = 0; r < 4; ++r) {
      int sl = t0 + wave*16 + row_l + r;
      if (sl < cnt) {
        int slot = base + sl;
        // exactly 2 atomic contributions per out element from 0 -> order-invariant (a+b==b+a)
        atomicAdd(&out[(size_t)stok[slot] * H_DIM + h0 + s*16 + col], sw[slot] * acc[s][r]);
      }
    }
  }
}

extern "C" void kernel_launch(void* const* d_in, const int* in_sizes, int n_in,
                              void* d_out, int out_size, void* d_ws, size_t ws_size,
                              hipStream_t stream) {
  const float* x  = (const float*)d_in[0];
  const float* rw = (const float*)d_in[1];
  const float* gw = (const float*)d_in[2];
  const float* uw = (const float*)d_in[3];
  const float* dw = (const float*)d_in[4];
  float* out = (float*)d_out;
  char* ws = (char*)d_ws;

  unsigned short* xbf = (unsigned short*)(ws + OFF_XBF);
  unsigned short* hid = (unsigned short*)(ws + OFF_HID);
  int*   stok    = (int*)(ws + OFF_STOK);
  float* swt     = (float*)(ws + OFF_SW);
  int*   tope    = (int*)(ws + OFF_TOPE);
  float* topw    = (float*)(ws + OFF_TOPW);
  int*   counts  = (int*)(ws + OFF_CNT);
  int*   cursors = (int*)(ws + OFF_CUR);
  int*   offs    = (int*)(ws + OFF_OFFS);

  hipMemsetAsync(ws + OFF_CNT, 0, 2048, stream);  // counts + cursors (padded)
  hipMemsetAsync(d_out, 0, (size_t)T_TOK * H_DIM * sizeof(float), stream);

  k_router<<<T_TOK / 4, 256, 0, stream>>>(x, rw, xbf, tope, topw);
  k_hist<<<T_TOK * 2 / 256, 256, 0, stream>>>(tope, counts);
  k_offsets<<<1, 64, 0, stream>>>(counts, offs);
  k_scatter<<<T_TOK / 256, 256, 0, stream>>>(tope, topw, offs, cursors, stok, swt);
  k_gateup<<<dim3(F_DIM / 64, T_TOK / 64, E_NUM), 256, 0, stream>>>(
      xbf, gw, uw, stok, counts, offs, hid);
  k_down<<<dim3(H_DIM / 64, T_TOK / 64, E_NUM), 256, 0, stream>>>(
      hid, dw, stok, swt, counts, offs, out);
}

// Round 3
// 172.048 us; speedup vs baseline: 3.2025x; 1.8976x over previous
//
#include <hip/hip_runtime.h>
#include <cstdint>
#include <cstddef>

#define T_TOK 8192
#define H_DIM 512
#define E_NUM 16
#define F_DIM 1024

typedef __bf16 bf16x8 __attribute__((ext_vector_type(8)));
typedef float f32x4 __attribute__((ext_vector_type(4)));

// ws layout (bytes) — total ~92.6 MB
#define OFF_XBF  0UL          // 8192*512*2            = 8,388,608
#define OFF_HID  8388608UL    // 16384*1024*2          = 33,554,432
#define OFF_GW   41943040UL   // 16 MB bf16 tiled gate
#define OFF_UW   58720256UL   // 16 MB bf16 tiled up
#define OFF_DW   75497472UL   // 16 MB bf16 tiled down
#define OFF_STOK 92274688UL
#define OFF_SW   92340224UL
#define OFF_TOPE 92405760UL
#define OFF_TOPW 92471296UL
#define OFF_CNT  92536832UL
#define OFF_CUR  92537856UL
#define OFF_OFFS 92538880UL

__device__ __forceinline__ unsigned short f2bf(float f) {
  union { float f; uint32_t u; } v; v.f = f;
  uint32_t r = v.u + 0x7fffu + ((v.u >> 16) & 1u);
  return (unsigned short)(r >> 16);
}

__device__ __forceinline__ void gld16(const void* g, void* l) {
  __builtin_amdgcn_global_load_lds(
      (const __attribute__((address_space(1))) unsigned int*)g,
      (__attribute__((address_space(3))) unsigned int*)l, 16, 0, 0);
}

// ---------------- routing: wave per token ----------------
__global__ __launch_bounds__(256) void k_router(
    const float* __restrict__ x, const float* __restrict__ rw,
    unsigned short* __restrict__ xbf, int* __restrict__ tope,
    float* __restrict__ topw) {
  const int wave = threadIdx.x >> 6, lane = threadIdx.x & 63;
  const int t = blockIdx.x * 4 + wave;
  const float4* xr = (const float4*)(x + (size_t)t * H_DIM + lane * 8);
  float4 a = xr[0], b = xr[1];
  float xi[8] = {a.x, a.y, a.z, a.w, b.x, b.y, b.z, b.w};
  uint4 o;
  o.x = (uint32_t)f2bf(xi[0]) | ((uint32_t)f2bf(xi[1]) << 16);
  o.y = (uint32_t)f2bf(xi[2]) | ((uint32_t)f2bf(xi[3]) << 16);
  o.z = (uint32_t)f2bf(xi[4]) | ((uint32_t)f2bf(xi[5]) << 16);
  o.w = (uint32_t)f2bf(xi[6]) | ((uint32_t)f2bf(xi[7]) << 16);
  *(uint4*)(xbf + (size_t)t * H_DIM + lane * 8) = o;
  float acc[E_NUM];
  #pragma unroll
  for (int e = 0; e < E_NUM; ++e) {
    const float4* wr = (const float4*)(rw + e * H_DIM + lane * 8);
    float4 wa = wr[0], wb = wr[1];
    acc[e] = xi[0]*wa.x + xi[1]*wa.y + xi[2]*wa.z + xi[3]*wa.w
           + xi[4]*wb.x + xi[5]*wb.y + xi[6]*wb.z + xi[7]*wb.w;
  }
  #pragma unroll
  for (int off = 1; off < 64; off <<= 1) {
    #pragma unroll
    for (int e = 0; e < E_NUM; ++e) acc[e] += __shfl_xor(acc[e], off);
  }
  if (lane == 0) {
    int e0 = 0; float v0 = acc[0];
    #pragma unroll
    for (int e = 1; e < E_NUM; ++e) if (acc[e] > v0) { v0 = acc[e]; e0 = e; }
    int e1 = -1; float v1 = -3.4e38f;
    #pragma unroll
    for (int e = 0; e < E_NUM; ++e) if (e != e0 && acc[e] > v1) { v1 = acc[e]; e1 = e; }
    float ee = __expf(v1 - v0);
    float inv = 1.0f / (1.0f + ee);
    tope[t*2]   = e0; tope[t*2+1] = e1;
    topw[t*2]   = inv; topw[t*2+1] = ee * inv;
  }
}

__global__ __launch_bounds__(256) void k_hist(
    const int* __restrict__ tope, int* __restrict__ counts) {
  __shared__ int lh[E_NUM];
  const int tid = threadIdx.x;
  if (tid < E_NUM) lh[tid] = 0;
  __syncthreads();
  atomicAdd(&lh[tope[blockIdx.x * 256 + tid]], 1);
  __syncthreads();
  if (tid < E_NUM) atomicAdd(&counts[tid * 16], lh[tid]);
}

__global__ void k_offsets(const int* __restrict__ counts, int* __restrict__ offs) {
  if (threadIdx.x == 0 && blockIdx.x == 0) {
    int s = 0;
    for (int e = 0; e < E_NUM; ++e) { offs[e] = s; s += counts[e * 16]; }
    offs[E_NUM] = s;
  }
}

__global__ __launch_bounds__(256) void k_scatter(
    const int* __restrict__ tope, const float* __restrict__ topw,
    const int* __restrict__ offs, int* __restrict__ cursors,
    int* __restrict__ stok, float* __restrict__ sw) {
  __shared__ int lh[E_NUM];
  __shared__ int lbase[E_NUM];
  const int tid = threadIdx.x;
  const int t = blockIdx.x * 256 + tid;
  if (tid < E_NUM) lh[tid] = 0;
  __syncthreads();
  int e0 = tope[t*2], e1 = tope[t*2+1];
  int r0 = atomicAdd(&lh[e0], 1);
  int r1 = atomicAdd(&lh[e1], 1);
  __syncthreads();
  if (tid < E_NUM) lbase[tid] = atomicAdd(&cursors[tid * 16], lh[tid]);
  __syncthreads();
  int s0 = offs[e0] + lbase[e0] + r0;
  int s1 = offs[e1] + lbase[e1] + r1;
  stok[s0] = t; sw[s0] = topw[t*2];
  stok[s1] = t; sw[s1] = topw[t*2+1];
}

// ---------------- weight prep: fp32 [k][n] -> bf16 tiles [n-tile rows][32k], XOR-swizzled ----------------
// gate/up: tiles [e][ftile=8][kchunk=16] of [128 f][4 slots of 16B]
__global__ __launch_bounds__(256) void k_prep_gu(
    const float* __restrict__ gw, const float* __restrict__ uw,
    unsigned short* __restrict__ gws, unsigned short* __restrict__ uws) {
  const int fx = blockIdx.x, kc = blockIdx.y, ez = blockIdx.z;
  const int e = ez >> 1;
  const float* src = ((ez & 1) ? uw : gw) + (size_t)e * H_DIM * F_DIM;
  unsigned short* dst = ((ez & 1) ? uws : gws);
  __shared__ float ls[32][132];
  const int tid = threadIdx.x;
  #pragma unroll
  for (int j = 0; j < 4; ++j) {
    int vi = tid + j * 256;
    int row = vi >> 5, c4 = (vi & 31) * 4;
    float4 v = *(const float4*)&src[(size_t)(kc*32 + row) * F_DIM + fx*128 + c4];
    ls[row][c4+0]=v.x; ls[row][c4+1]=v.y; ls[row][c4+2]=v.z; ls[row][c4+3]=v.w;
  }
  __syncthreads();
  size_t obase = (((size_t)e * 8 + fx) * 16 + kc) * 4096;  // ushorts
  #pragma unroll
  for (int j = 0; j < 2; ++j) {
    int oi = tid + j * 256;
    int f = oi >> 2, slot = oi & 3;
    int ks = ((slot ^ f) & 3) * 8;
    uint4 o;
    o.x = (uint32_t)f2bf(ls[ks+0][f]) | ((uint32_t)f2bf(ls[ks+1][f]) << 16);
    o.y = (uint32_t)f2bf(ls[ks+2][f]) | ((uint32_t)f2bf(ls[ks+3][f]) << 16);
    o.z = (uint32_t)f2bf(ls[ks+4][f]) | ((uint32_t)f2bf(ls[ks+5][f]) << 16);
    o.w = (uint32_t)f2bf(ls[ks+6][f]) | ((uint32_t)f2bf(ls[ks+7][f]) << 16);
    *(uint4*)&dst[obase + (size_t)oi * 8] = o;
  }
}

// down: tiles [e][htile=2][kchunk=32] of [256 h][4 slots]
__global__ __launch_bounds__(256) void k_prep_dw(
    const float* __restrict__ dw, unsigned short* __restrict__ dws) {
  const int ht = blockIdx.x, kc = blockIdx.y, e = blockIdx.z;
  const float* src = dw + (size_t)e * F_DIM * H_DIM;
  __shared__ float ls[32][260];
  const int tid = threadIdx.x;
  #pragma unroll
  for (int j = 0; j < 8; ++j) {
    int vi = tid + j * 256;
    int row = vi >> 6, c4 = (vi & 63) * 4;
    float4 v = *(const float4*)&src[(size_t)(kc*32 + row) * H_DIM + ht*256 + c4];
    ls[row][c4+0]=v.x; ls[row][c4+1]=v.y; ls[row][c4+2]=v.z; ls[row][c4+3]=v.w;
  }
  __syncthreads();
  size_t obase = (((size_t)e * 2 + ht) * 32 + kc) * 8192;  // ushorts
  #pragma unroll
  for (int j = 0; j < 4; ++j) {
    int oi = tid + j * 256;
    int h = oi >> 2, slot = oi & 3;
    int ks = ((slot ^ h) & 3) * 8;
    uint4 o;
    o.x = (uint32_t)f2bf(ls[ks+0][h]) | ((uint32_t)f2bf(ls[ks+1][h]) << 16);
    o.y = (uint32_t)f2bf(ls[ks+2][h]) | ((uint32_t)f2bf(ls[ks+3][h]) << 16);
    o.z = (uint32_t)f2bf(ls[ks+4][h]) | ((uint32_t)f2bf(ls[ks+5][h]) << 16);
    o.w = (uint32_t)f2bf(ls[ks+6][h]) | ((uint32_t)f2bf(ls[ks+7][h]) << 16);
    *(uint4*)&dws[obase + (size_t)oi * 8] = o;
  }
}

// ---------------- gate/up GEMM + SiLU ----------------
// block: 128 tokens x 128 f, 4 waves (2x2), BK=32, 16 chunks, global_load_lds + swizzle
__global__ __launch_bounds__(256, 2) void k_gateup(
    const unsigned short* __restrict__ xbf,
    const unsigned short* __restrict__ gws, const unsigned short* __restrict__ uws,
    const int* __restrict__ stok, const int* __restrict__ counts,
    const int* __restrict__ offs, unsigned short* __restrict__ hid) {
  const int e = blockIdx.z;
  const int cnt = counts[e * 16];
  const int t0 = blockIdx.y * 128;
  if (t0 >= cnt) return;
  const int base = offs[e];
  const int fx = blockIdx.x;

  __shared__ __align__(16) unsigned short sb[2][3][4096];  // A,G,U  48 KB

  const int tid = threadIdx.x;
  const int wave = tid >> 6, lane = tid & 63;
  const int l15 = lane & 15, hi = lane >> 4;
  const int wm = wave >> 1, wn = wave & 1;

  // A gather sources (per-lane global addr, wave-uniform LDS dest)
  const int r0 = tid >> 2, slot = tid & 3;
  const int rr0 = min(t0 + r0, cnt - 1), rr1 = min(t0 + r0 + 64, cnt - 1);
  const char* sA0 = (const char*)xbf + (size_t)stok[base + rr0] * 1024 + ((slot ^ (r0 & 3)) * 16);
  const char* sA1 = (const char*)xbf + (size_t)stok[base + rr1] * 1024 + ((slot ^ (r0 & 3)) * 16);
  const char* sG = (const char*)gws + (((size_t)e * 8 + fx) * 16) * 8192 + tid * 16;
  const char* sU = (const char*)uws + (((size_t)e * 8 + fx) * 16) * 8192 + tid * 16;
  unsigned short* const dA = &sb[0][0][wave * 512];
  unsigned short* const dG = &sb[0][1][wave * 512];
  unsigned short* const dU = &sb[0][2][wave * 512];
  const int bufo = 3 * 4096;  // ushort stride between buffers

  f32x4 accg[4][4] = {}; f32x4 accu[4][4] = {};

  #define STAGE_GU(b, kk) { \
    gld16(sA0 + (kk)*64, dA + (b)*bufo); \
    gld16(sA1 + (kk)*64, dA + (b)*bufo + 2048); \
    gld16(sG + (size_t)(kk)*8192, dG + (b)*bufo); \
    gld16(sG + (size_t)(kk)*8192 + 4096, dG + (b)*bufo + 2048); \
    gld16(sU + (size_t)(kk)*8192, dU + (b)*bufo); \
    gld16(sU + (size_t)(kk)*8192 + 4096, dU + (b)*bufo + 2048); }

  STAGE_GU(0, 0);
  __syncthreads();
  #pragma unroll 1
  for (int kk = 0; kk < 16; ++kk) {
    const int cur = kk & 1;
    if (kk < 15) STAGE_GU(cur ^ 1, kk + 1);
    const unsigned short* lA = &sb[cur][0][0];
    const unsigned short* lG = &sb[cur][1][0];
    const unsigned short* lU = &sb[cur][2][0];
    bf16x8 a[4], bg[4], bu[4];
    #pragma unroll
    for (int m = 0; m < 4; ++m) {
      int row = wm*64 + m*16 + l15;
      a[m] = *(const bf16x8*)((const char*)lA + row*64 + (((hi ^ row) & 3) << 4));
    }
    #pragma unroll
    for (int s = 0; s < 4; ++s) {
      int row = wn*64 + s*16 + l15;
      int o = row*64 + (((hi ^ row) & 3) << 4);
      bg[s] = *(const bf16x8*)((const char*)lG + o);
      bu[s] = *(const bf16x8*)((const char*)lU + o);
    }
    #pragma unroll
    for (int m = 0; m < 4; ++m)
      #pragma unroll
      for (int s = 0; s < 4; ++s) {
        accg[m][s] = __builtin_amdgcn_mfma_f32_16x16x32_bf16(a[m], bg[s], accg[m][s], 0, 0, 0);
        accu[m][s] = __builtin_amdgcn_mfma_f32_16x16x32_bf16(a[m], bu[s], accu[m][s], 0, 0, 0);
      }
    __syncthreads();
  }
  #undef STAGE_GU

  #pragma unroll
  for (int m = 0; m < 4; ++m)
    #pragma unroll
    for (int r = 0; r < 4; ++r) {
      int row = t0 + wm*64 + m*16 + hi*4 + r;
      if (row < cnt) {
        #pragma unroll
        for (int s = 0; s < 4; ++s) {
          float g = accg[m][s][r], u = accu[m][s][r];
          float h = g / (1.0f + __expf(-g)) * u;
          hid[(size_t)(base + row) * 1024 + fx*128 + wn*64 + s*16 + l15] = f2bf(h);
        }
      }
    }
}

// ---------------- down GEMM + weighted scatter ----------------
// block: 128 tokens x 256 h, 4 waves (2x2, wave = 64t x 128h), BK=32, 32 chunks
__global__ __launch_bounds__(256, 2) void k_down(
    const unsigned short* __restrict__ hid, const unsigned short* __restrict__ dws,
    const int* __restrict__ stok, const float* __restrict__ sw,
    const int* __restrict__ counts, const int* __restrict__ offs,
    float* __restrict__ out) {
  const int e = blockIdx.z;
  const int cnt = counts[e * 16];
  const int t0 = blockIdx.y * 128;
  if (t0 >= cnt) return;
  const int base = offs[e];
  const int ht = blockIdx.x;

  __shared__ __align__(16) unsigned short sbA[2][4096];   // 16 KB
  __shared__ __align__(16) unsigned short sbW[2][8192];   // 32 KB

  const int tid = threadIdx.x;
  const int wave = tid >> 6, lane = tid & 63;
  const int l15 = lane & 15, hi = lane >> 4;
  const int wm = wave >> 1, wn = wave & 1;

  const int r0 = tid >> 2, slot = tid & 3;
  const int rr0 = min(t0 + r0, cnt - 1), rr1 = min(t0 + r0 + 64, cnt - 1);
  const char* sA0 = (const char*)hid + (size_t)(base + rr0) * 2048 + ((slot ^ (r0 & 3)) * 16);
  const char* sA1 = (const char*)hid + (size_t)(base + rr1) * 2048 + ((slot ^ (r0 & 3)) * 16);
  const char* sW = (const char*)dws + (((size_t)e * 2 + ht) * 32) * 16384 + tid * 16;
  unsigned short* const dA = &sbA[0][wave * 512];
  unsigned short* const dW = &sbW[0][wave * 512];

  f32x4 acc[4][8] = {};

  #define STAGE_DN(b, kk) { \
    gld16(sA0 + (kk)*64, dA + (b)*4096); \
    gld16(sA1 + (kk)*64, dA + (b)*4096 + 2048); \
    const char* w = sW + (size_t)(kk)*16384; \
    gld16(w,        dW + (b)*8192); \
    gld16(w + 4096, dW + (b)*8192 + 2048); \
    gld16(w + 8192, dW + (b)*8192 + 4096); \
    gld16(w + 12288, dW + (b)*8192 + 6144); }

  STAGE_DN(0, 0);
  __syncthreads();
  #pragma unroll 1
  for (int kk = 0; kk < 32; ++kk) {
    const int cur = kk & 1;
    if (kk < 31) STAGE_DN(cur ^ 1, kk + 1);
    const unsigned short* lA = &sbA[cur][0];
    const unsigned short* lW = &sbW[cur][0];
    bf16x8 a[4], b[8];
    #pragma unroll
    for (int m = 0; m < 4; ++m) {
      int row = wm*64 + m*16 + l15;
      a[m] = *(const bf16x8*)((const char*)lA + row*64 + (((hi ^ row) & 3) << 4));
    }
    #pragma unroll
    for (int s = 0; s < 8; ++s) {
      int row = wn*128 + s*16 + l15;
      b[s] = *(const bf16x8*)((const char*)lW + row*64 + (((hi ^ row) & 3) << 4));
    }
    #pragma unroll
    for (int m = 0; m < 4; ++m)
      #pragma unroll
      for (int s = 0; s < 8; ++s)
        acc[m][s] = __builtin_amdgcn_mfma_f32_16x16x32_bf16(a[m], b[s], acc[m][s], 0, 0, 0);
    __syncthreads();
  }
  #undef STAGE_DN

  #pragma unroll
  for (int m = 0; m < 4; ++m)
    #pragma unroll
    for (int r = 0; r < 4; ++r) {
      int row = t0 + wm*64 + m*16 + hi*4 + r;
      if (row < cnt) {
        int sl = base + row;
        int t = stok[sl];
        float w = sw[sl];
        float* orow = out + (size_t)t * H_DIM + ht*256 + wn*128;
        #pragma unroll
        for (int s = 0; s < 8; ++s)
          atomicAdd(&orow[s*16 + l15], w * acc[m][s][r]);
      }
    }
}

extern "C" void kernel_launch(void* const* d_in, const int* in_sizes, int n_in,
                              void* d_out, int out_size, void* d_ws, size_t ws_size,
                              hipStream_t stream) {
  const float* x  = (const float*)d_in[0];
  const float* rw = (const float*)d_in[1];
  const float* gw = (const float*)d_in[2];
  const float* uw = (const float*)d_in[3];
  const float* dw = (const float*)d_in[4];
  float* out = (float*)d_out;
  char* ws = (char*)d_ws;

  unsigned short* xbf = (unsigned short*)(ws + OFF_XBF);
  unsigned short* hid = (unsigned short*)(ws + OFF_HID);
  unsigned short* gws = (unsigned short*)(ws + OFF_GW);
  unsigned short* uws = (unsigned short*)(ws + OFF_UW);
  unsigned short* dws = (unsigned short*)(ws + OFF_DW);
  int*   stok    = (int*)(ws + OFF_STOK);
  float* swt     = (float*)(ws + OFF_SW);
  int*   tope    = (int*)(ws + OFF_TOPE);
  float* topw    = (float*)(ws + OFF_TOPW);
  int*   counts  = (int*)(ws + OFF_CNT);
  int*   cursors = (int*)(ws + OFF_CUR);
  int*   offs    = (int*)(ws + OFF_OFFS);

  hipMemsetAsync(ws + OFF_CNT, 0, 2048 + 128, stream);
  hipMemsetAsync(d_out, 0, (size_t)T_TOK * H_DIM * sizeof(float), stream);

  k_prep_gu<<<dim3(8, 16, 32), 256, 0, stream>>>(gw, uw, gws, uws);
  k_prep_dw<<<dim3(2, 32, 16), 256, 0, stream>>>(dw, dws);
  k_router<<<T_TOK / 4, 256, 0, stream>>>(x, rw, xbf, tope, topw);
  k_hist<<<T_TOK * 2 / 256, 256, 0, stream>>>(tope, counts);
  k_offsets<<<1, 64, 0, stream>>>(counts, offs);
  k_scatter<<<T_TOK / 256, 256, 0, stream>>>(tope, topw, offs, cursors, stok, swt);
  k_gateup<<<dim3(8, T_TOK * 2 / 128, E_NUM), 256, 0, stream>>>(
      xbf, gws, uws, stok, counts, offs, hid);
  k_down<<<dim3(2, T_TOK * 2 / 128, E_NUM), 256, 0, stream>>>(
      hid, dws, stok, swt, counts, offs, out);
}